// Round 2
// baseline (186.854 us; speedup 1.0000x reference)
//
#include <hip/hip_runtime.h>

// Problem constants (from reference)
constexpr int B  = 8;
constexpr int T  = 256;
constexpr int U1 = 65;
constexpr int DK = 640;   // D_ENC == D_pred
constexpr int V  = 1024;

constexpr int M_ENC  = B * T;    // 2048
constexpr int M_PRED = B * U1;   // 520

constexpr int TM = 16;                              // rows per block tile
constexpr int NB_ENC  = M_ENC / TM;                 // 128
constexpr int NB_PRED = (M_PRED + TM - 1) / TM;     // 33
constexpr int COLSPLIT = 2;                         // 512 cols per block
constexpr int NCOL4 = (V / COLSPLIT) / 4;           // 128 float4 per col-half

typedef float f32x4 __attribute__((ext_vector_type(4)));

__device__ __forceinline__ void fma4(float a, const float4& wv, float4& c) {
    c.x = fmaf(a, wv.x, c.x);
    c.y = fmaf(a, wv.y, c.y);
    c.z = fmaf(a, wv.z, c.z);
    c.w = fmaf(a, wv.w, c.w);
}

// Computes enc_proj = enc @ W[:640] and pred_proj = pred @ W[640:] + b.
// Grid: (NB_ENC + NB_PRED) * COLSPLIT blocks, 256 threads.
__global__ __launch_bounds__(256) void proj_kernel(
    const float* __restrict__ enc, const float* __restrict__ pred,
    const float* __restrict__ W, const float* __restrict__ bias,
    float* __restrict__ enc_proj, float* __restrict__ pred_proj)
{
    __shared__ float a_s[TM * DK];   // 40 KB

    const int tid      = threadIdx.x;
    const int rowblock = blockIdx.x >> 1;           // which 16-row tile
    const int colhalf  = blockIdx.x & 1;            // which 512-col half

    const bool isEnc = (rowblock < NB_ENC);
    const float* A   = isEnc ? enc : pred;
    float* O         = isEnc ? enc_proj : pred_proj;
    const float* Wb  = isEnc ? W : (W + (size_t)DK * V);
    const int M      = isEnc ? M_ENC : M_PRED;
    const int row0   = (isEnc ? rowblock : (rowblock - NB_ENC)) * TM;

    // ---- stage A tile (16 rows x 640 f32, contiguous in global) into LDS ----
    {
        const float4* Ag = reinterpret_cast<const float4*>(A + (size_t)row0 * DK);
        float4* As = reinterpret_cast<float4*>(a_s);
        const int nf4 = TM * DK / 4;                // 2560
        for (int i = tid; i < nf4; i += 256) {
            int r = i / (DK / 4);                   // row within tile
            float4 v = make_float4(0.f, 0.f, 0.f, 0.f);
            if (row0 + r < M) v = Ag[i];
            As[i] = v;
        }
    }
    __syncthreads();

    // thread mapping: tx = col float4 slot (0..127), rh = row half (0/1 -> 8 rows)
    const int tx = tid & (NCOL4 - 1);
    const int rh = tid >> 7;

    float4 acc[8];
    #pragma unroll
    for (int r = 0; r < 8; ++r) acc[r] = make_float4(0.f, 0.f, 0.f, 0.f);

    const float4* W4 = reinterpret_cast<const float4*>(Wb)
                       + (size_t)colhalf * NCOL4 + tx;   // column of W, stride V/4 per d

    for (int d = 0; d < DK; d += 4) {
        float4 w0 = W4[(size_t)(d + 0) * (V / 4)];
        float4 w1 = W4[(size_t)(d + 1) * (V / 4)];
        float4 w2 = W4[(size_t)(d + 2) * (V / 4)];
        float4 w3 = W4[(size_t)(d + 3) * (V / 4)];
        #pragma unroll
        for (int r = 0; r < 8; ++r) {
            const float4 av = *reinterpret_cast<const float4*>(
                &a_s[(rh * 8 + r) * DK + d]);      // wave-uniform -> LDS broadcast
            fma4(av.x, w0, acc[r]);
            fma4(av.y, w1, acc[r]);
            fma4(av.z, w2, acc[r]);
            fma4(av.w, w3, acc[r]);
        }
    }

    // ---- epilogue: (+bias for pred rows), float4 store ----
    float4 bv = make_float4(0.f, 0.f, 0.f, 0.f);
    if (!isEnc) bv = reinterpret_cast<const float4*>(bias)[colhalf * NCOL4 + tx];

    #pragma unroll
    for (int r = 0; r < 8; ++r) {
        const int row = row0 + rh * 8 + r;
        if (row < M) {
            float4 o = acc[r];
            o.x += bv.x; o.y += bv.y; o.z += bv.z; o.w += bv.w;
            reinterpret_cast<float4*>(O)[(size_t)row * (V / 4) + colhalf * NCOL4 + tx] = o;
        }
    }
}

// out[b,t,u,v] = enc_proj[b,t,v] + pred_proj[b,u,v]   (bias already folded in)
// Grid: B*T blocks (one per (b,t)), 256 threads; each thread owns one float4 of V.
__global__ __launch_bounds__(256) void bcast_kernel(
    const float* __restrict__ enc_proj, const float* __restrict__ pred_proj,
    float* __restrict__ out)
{
    const int bt  = blockIdx.x;          // 0..2047
    const int b   = bt >> 8;             // T = 256
    const int tid = threadIdx.x;

    const f32x4* e4 = reinterpret_cast<const f32x4*>(enc_proj) + (size_t)bt * (V / 4);
    const f32x4* p4 = reinterpret_cast<const f32x4*>(pred_proj) + (size_t)b * U1 * (V / 4);
    f32x4* o4       = reinterpret_cast<f32x4*>(out) + (size_t)bt * U1 * (V / 4);

    const f32x4 e = e4[tid];

    #pragma unroll 4
    for (int u = 0; u < U1; ++u) {
        f32x4 p = p4[(size_t)u * (V / 4) + tid];
        f32x4 o = e + p;
        __builtin_nontemporal_store(o, &o4[(size_t)u * (V / 4) + tid]);
    }
}

extern "C" void kernel_launch(void* const* d_in, const int* in_sizes, int n_in,
                              void* d_out, int out_size, void* d_ws, size_t ws_size,
                              hipStream_t stream)
{
    const float* enc  = (const float*)d_in[0];   // (8,256,640)
    const float* pred = (const float*)d_in[1];   // (8,65,640)
    const float* W    = (const float*)d_in[2];   // (1280,1024)
    const float* bias = (const float*)d_in[3];   // (1024,)
    float* out = (float*)d_out;                  // (8,256,65,1024)

    float* enc_proj  = (float*)d_ws;                         // 2048*1024 f32 = 8 MiB
    float* pred_proj = enc_proj + (size_t)M_ENC * V;         // 520*1024  f32 = 2 MiB

    proj_kernel<<<(NB_ENC + NB_PRED) * COLSPLIT, 256, 0, stream>>>(
        enc, pred, W, bias, enc_proj, pred_proj);

    bcast_kernel<<<M_ENC, 256, 0, stream>>>(enc_proj, pred_proj, out);
}